// Round 16
// baseline (69.639 us; speedup 1.0000x reference)
//
#include <hip/hip_runtime.h>

#define B_TOT 1024   // BATCH * nbr = 64 * 16
#define L_DIM 64
#define K_DIM 32
#define OUT_K 32
#define EPS_BN 1e-5f

typedef __attribute__((ext_vector_type(8))) short short8;
typedef __attribute__((ext_vector_type(4))) short short4v;
typedef __attribute__((ext_vector_type(4))) float f32x4;

__device__ __forceinline__ float reduce64(float v) {
    #pragma unroll
    for (int w = 1; w < 64; w <<= 1) v += __shfl_xor(v, w);
    return v;
}

// DPP fused-add reduction step (VALU, zero LDS-pipe traffic).
template<int CTRL, int RM>
__device__ __forceinline__ float dppadd(float v) {
    return v + __int_as_float(__builtin_amdgcn_update_dpp(
        0, __float_as_int(v), CTRL, RM, 0xF, true));
}
// wave64 sum -> lane 63
__device__ __forceinline__ float sum64_dpp(float v) {
    v = dppadd<0x111, 0xF>(v);
    v = dppadd<0x112, 0xF>(v);
    v = dppadd<0x114, 0xF>(v);
    v = dppadd<0x118, 0xF>(v);
    v = dppadd<0x142, 0xA>(v);  // row_bcast15
    v = dppadd<0x143, 0xC>(v);  // row_bcast31
    return v;
}
// 32-lane sums -> lanes 31 and 63
__device__ __forceinline__ float sum32_dpp(float v) {
    v = dppadd<0x111, 0xF>(v);
    v = dppadd<0x112, 0xF>(v);
    v = dppadd<0x114, 0xF>(v);
    v = dppadd<0x118, 0xF>(v);
    v = dppadd<0x142, 0xA>(v);
    return v;
}
// 16-lane (row) sums -> lane 15 of each row
__device__ __forceinline__ float sum16_dpp(float v) {
    v = dppadd<0x111, 0xF>(v);
    v = dppadd<0x112, 0xF>(v);
    v = dppadd<0x114, 0xF>(v);
    v = dppadd<0x118, 0xF>(v);
    return v;
}

__device__ __forceinline__ unsigned short f2bf(float x) {
    unsigned int u = __float_as_uint(x);
    u += 0x7FFF + ((u >> 16) & 1);   // RNE
    return (unsigned short)(u >> 16);
}

// ---------------------------------------------------------------------------
// hmeans + fused layer-0 stats + (block B_TOT) weight prep (DPP reductions).
// ---------------------------------------------------------------------------
__global__ __launch_bounds__(256, 4) void hmeans_l0_kernel(
    const float* __restrict__ Hr, const float* __restrict__ Hi,
    float* __restrict__ Hmk, float* __restrict__ Hml,
    const float* __restrict__ P0,   // layer0: P1a | P1u
    float* __restrict__ muS, float* __restrict__ muQ,
    const float* __restrict__ Qh1,  // layer-1 Q base (prep)
    const float* __restrict__ P1h,  // layer-1 P base (prep)
    const float* __restrict__ Qo,   // out-layer Q base (prep)
    const float* __restrict__ Po,   // out-layer P base (prep)
    unsigned short* __restrict__ Qpack_ap,
    unsigned short* __restrict__ Qpack_ue,
    unsigned short* __restrict__ Qpack_o) {
    int b = blockIdx.x, tid = threadIdx.x;

    if (b == B_TOT) {
        // ---- weight-prep block ----
        const float* Q1a = Qh1;
        const float* Q1u = Qh1 + 2 * 4096;
        const float* P1a = P1h;
        const float* P1u = P1h + 512;
        for (int idx = tid; idx < 6144; idx += 256) {
            int j = idx & 7, lane = (idx >> 3) & 63, ot = (idx >> 9) & 3, kt = idx >> 11;
            int m = lane & 15, kloc = (lane >> 4) * 8 + j;
            int o = ot * 16 + m, k = kt * 32 + kloc;
            float va = 0.f, vu = 0.f;
            if (k < 64)      { va = 2.0f * Q1a[o * 64 + k]; vu = 2.0f * Q1u[o * 64 + k]; }
            else if (k < 72) { va = 0.1f * P1a[o * 8 + (k - 64)]; vu = 0.1f * P1u[o * 8 + (k - 64)]; }
            Qpack_ap[idx] = f2bf(va);
            Qpack_ue[idx] = f2bf(vu);
        }
        // out-layer pack: 2 o-tiles x 3 k-tiles; cols 0..63 = 2*Q1o,
        // 64..71 = 0.1*P1o, 72..95 = 0
        for (int idx = tid; idx < 3072; idx += 256) {
            int j = idx & 7, lane = (idx >> 3) & 63, ot = (idx >> 9) & 1, kt = idx >> 10;
            int m = lane & 15, kloc = (lane >> 4) * 8 + j;
            int o = ot * 16 + m, k = kt * 32 + kloc;
            float v = 0.f;
            if (k < 64)      v = 2.0f * Qo[o * 64 + k];
            else if (k < 72) v = 0.1f * Po[o * 8 + (k - 64)];
            Qpack_o[idx] = f2bf(v);
        }
        return;
    }

    __shared__ float hmkS[512];      // [c][l]
    __shared__ float hmlS[256];      // [c][k]
    __shared__ float4 wpart[4][32];  // [wave][k]
    int w = tid >> 6, lane = tid & 63;
    int g = tid >> 5, k = tid & 31;

    for (int ri = 0; ri < 2; ++ri) {
        const float4* src4 = (const float4*)((ri ? Hi : Hr) + (size_t)b * 8192);
        float4 v[8];
        #pragma unroll
        for (int s = 0; s < 8; ++s) v[s] = src4[tid + 256 * s];

        float4 part = v[0];
        #pragma unroll
        for (int s = 1; s < 8; ++s) {
            part.x += v[s].x; part.y += v[s].y;
            part.z += v[s].z; part.w += v[s].w;
        }

        #pragma unroll
        for (int s = 0; s < 8; ++s) {
            float rx = sum32_dpp(v[s].x);
            float ry = sum32_dpp(v[s].y);
            float rz = sum32_dpp(v[s].z);
            float rw = sum32_dpp(v[s].w);
            if ((lane & 31) == 31) {
                int l = g + 8 * s;
                const float sc = 1.0f / 32.0f;
                hmkS[(ri * 4 + 0) * 64 + l] = rx * sc;
                hmkS[(ri * 4 + 1) * 64 + l] = ry * sc;
                hmkS[(ri * 4 + 2) * 64 + l] = rz * sc;
                hmkS[(ri * 4 + 3) * 64 + l] = rw * sc;
            }
        }

        part.x += __shfl_xor(part.x, 32);
        part.y += __shfl_xor(part.y, 32);
        part.z += __shfl_xor(part.z, 32);
        part.w += __shfl_xor(part.w, 32);
        if (lane < 32) wpart[w][k] = part;
        __syncthreads();
        if (tid < 128) {
            int kk = tid >> 2, u = tid & 3;
            float s = ((const float*)&wpart[0][kk])[u]
                    + ((const float*)&wpart[1][kk])[u]
                    + ((const float*)&wpart[2][kk])[u]
                    + ((const float*)&wpart[3][kk])[u];
            hmlS[(ri * 4 + u) * 32 + kk] = s * (1.0f / 64.0f);
        }
        __syncthreads();
    }

    Hmk[(size_t)b * 512 + tid]       = hmkS[tid];
    Hmk[(size_t)b * 512 + 256 + tid] = hmkS[256 + tid];
    Hml[(size_t)b * 256 + tid]       = hmlS[tid];

    // ---- layer-0 stats ----
    int o0 = __builtin_amdgcn_readfirstlane(w << 4);
    float hmk[8], hml[8];
    #pragma unroll
    for (int c = 0; c < 8; ++c) hmk[c] = hmkS[c * 64 + lane];
    #pragma unroll
    for (int c = 0; c < 8; ++c) hml[c] = hmlS[c * 32 + (lane & 31)];

    for (int h = 0; h < 2; ++h) {
        float vs[8], qs[8];
        #pragma unroll
        for (int mm = 0; mm < 8; ++mm) {
            int o = o0 + h * 8 + mm;
            float4 p0 = *(const float4*)(P0 + o * 8);
            float4 p1 = *(const float4*)(P0 + o * 8 + 4);
            float pa = p0.x * hmk[0] + p0.y * hmk[1] + p0.z * hmk[2] + p0.w * hmk[3]
                     + p1.x * hmk[4] + p1.y * hmk[5] + p1.z * hmk[6] + p1.w * hmk[7];
            float v = fmaxf(0.1f * pa, 0.f);
            vs[mm] = sum64_dpp(v);
            qs[mm] = sum64_dpp(v * v);
        }
        if (lane == 63) {
            #pragma unroll
            for (int mm = 0; mm < 8; ++mm) {
                muS[b * 128 + o0 + h * 8 + mm] = vs[mm];
                muQ[b * 128 + o0 + h * 8 + mm] = qs[mm];
            }
        }
    }
    for (int h = 0; h < 2; ++h) {
        float vs[8], qs[8];
        #pragma unroll
        for (int mm = 0; mm < 8; ++mm) {
            int o = o0 + h * 8 + mm;
            float4 p0 = *(const float4*)(P0 + 512 + o * 8);
            float4 p1 = *(const float4*)(P0 + 512 + o * 8 + 4);
            float pu = p0.x * hml[0] + p0.y * hml[1] + p0.z * hml[2] + p0.w * hml[3]
                     + p1.x * hml[4] + p1.y * hml[5] + p1.z * hml[6] + p1.w * hml[7];
            float v = fmaxf(0.1f * pu, 0.f);
            vs[mm] = sum64_dpp(v);
            qs[mm] = sum64_dpp(v * v);
        }
        if (lane == 63) {
            #pragma unroll
            for (int mm = 0; mm < 8; ++mm) {
                muS[b * 128 + 64 + o0 + h * 8 + mm] = vs[mm] * 0.5f;
                muQ[b * 128 + 64 + o0 + h * 8 + mm] = qs[mm] * 0.5f;
            }
        }
    }
}

// ---------------------------------------------------------------------------
// Layer-1 stats via MFMA (no activation store; biasA computed in-kernel).
// One block per b (4 waves). (256,4): VGPR cap 128 -> up to 4 blocks/CU so
// the phase-serialized structure (stage->bias->MFMA) overlaps across blocks.
// ---------------------------------------------------------------------------
__global__ __launch_bounds__(256, 4) void l1stats_kernel(
    const float* __restrict__ Hmk, const float* __restrict__ Hml,
    const unsigned short* __restrict__ Qpack_ap,
    const unsigned short* __restrict__ Qpack_ue,
    const float* __restrict__ P0,
    const float* __restrict__ Qh1,     // layer-1 Q base (Q2a/Q2u rows)
    const float* __restrict__ coefA,
    const float* __restrict__ muS0,    // layer-0 raw sums
    float* __restrict__ muS1, float* __restrict__ muQ1) {
    __shared__ unsigned short Bap[64 * 104];
    __shared__ unsigned short Bue[32 * 104];
    __shared__ float mubn[128];
    __shared__ float biasS[128];
    int b = blockIdx.x, t = threadIdx.x;

    // ---- stage BN(A0_ap) + mubn ----
    {
        int l = t & 63, wid = t >> 6, i0 = wid << 4;
        float hmk[8];
        #pragma unroll
        for (int c = 0; c < 8; ++c) hmk[c] = Hmk[(size_t)b * 512 + c * 64 + l];
        unsigned short tmp[16];
        #pragma unroll
        for (int m = 0; m < 16; ++m) {
            int i = i0 + m;
            float4 p0 = *(const float4*)(P0 + i * 8);
            float4 p1 = *(const float4*)(P0 + i * 8 + 4);
            float pa = p0.x * hmk[0] + p0.y * hmk[1] + p0.z * hmk[2] + p0.w * hmk[3]
                     + p1.x * hmk[4] + p1.y * hmk[5] + p1.z * hmk[6] + p1.w * hmk[7];
            float a0 = fmaxf(0.1f * pa, 0.f);
            tmp[m] = f2bf(a0 * coefA[i] + coefA[64 + i]);
        }
        short8 s0, s1;
        #pragma unroll
        for (int j = 0; j < 8; ++j) { s0[j] = (short)tmp[j]; s1[j] = (short)tmp[8 + j]; }
        *(short8*)(&Bap[l * 104 + i0]) = s0;
        *(short8*)(&Bap[l * 104 + i0 + 8]) = s1;
        if (wid == 0) {
            #pragma unroll
            for (int c = 0; c < 8; ++c) Bap[l * 104 + 64 + c] = f2bf(hmk[c]);
            #pragma unroll
            for (int c = 72; c < 96; ++c) Bap[l * 104 + c] = 0;
        }
    }
    {
        int k = t & 31, g = t >> 5, i0 = g << 3;
        float hml[8];
        #pragma unroll
        for (int c = 0; c < 8; ++c) hml[c] = Hml[(size_t)b * 256 + c * 32 + k];
        unsigned short tu[8];
        #pragma unroll
        for (int m = 0; m < 8; ++m) {
            int i = i0 + m;
            float4 p0 = *(const float4*)(P0 + 512 + i * 8);
            float4 p1 = *(const float4*)(P0 + 512 + i * 8 + 4);
            float pu = p0.x * hml[0] + p0.y * hml[1] + p0.z * hml[2] + p0.w * hml[3]
                     + p1.x * hml[4] + p1.y * hml[5] + p1.z * hml[6] + p1.w * hml[7];
            float a0 = fmaxf(0.1f * pu, 0.f);
            tu[m] = f2bf(a0 * coefA[128 + i] + coefA[192 + i]);
        }
        short8 s0;
        #pragma unroll
        for (int j = 0; j < 8; ++j) s0[j] = (short)tu[j];
        *(short8*)(&Bue[k * 104 + i0]) = s0;
        if (t < 32) {
            #pragma unroll
            for (int c = 0; c < 8; ++c) Bue[k * 104 + 64 + c] = f2bf(hml[c]);
            #pragma unroll
            for (int c = 72; c < 96; ++c) Bue[k * 104 + c] = 0;
        }
    }
    if (t < 128) {
        float raw = muS0[b * 128 + t];
        mubn[t] = (t < 64)
            ? raw * (1.0f / 64.0f) * coefA[t] + coefA[64 + t]
            : raw * (1.0f / 32.0f) * coefA[64 + t] + coefA[128 + t];
    }
    __syncthreads();

    // ---- bias dots: biasS[o]=2*Q2a[o,:]@mubnUE, biasS[64+o]=2*Q2u[o,:]@mubnAP
    if (t < 128) {
        const float* Qm = (t < 64) ? (Qh1 + 4096) : (Qh1 + 3 * 4096);
        const float* mu = (t < 64) ? (mubn + 64) : mubn;
        int o = t & 63;
        const float4* Qrow = (const float4*)(Qm + o * 64);
        float sa = 0.f, sb = 0.f, sc2 = 0.f, sd = 0.f;
        #pragma unroll
        for (int j = 0; j < 16; ++j) {
            float4 q = Qrow[j];
            sa += q.x * mu[4 * j];
            sb += q.y * mu[4 * j + 1];
            sc2 += q.z * mu[4 * j + 2];
            sd += q.w * mu[4 * j + 3];
        }
        biasS[t] = 2.f * ((sa + sb) + (sc2 + sd));
    }
    __syncthreads();

    int lane = t & 63, w = t >> 6;
    int m16 = lane & 15, g4 = lane >> 4;
    int obase = w * 16 + g4 * 4;

    short8 aq[3], aqu[3];
    #pragma unroll
    for (int kt = 0; kt < 3; ++kt) {
        aq[kt]  = *(const short8*)(Qpack_ap + (((kt * 4 + w) * 64 + lane) << 3));
        aqu[kt] = *(const short8*)(Qpack_ue + (((kt * 4 + w) * 64 + lane) << 3));
    }

    // AP: 4 l-tiles, stats only
    float vsum[4] = {0.f, 0.f, 0.f, 0.f}, vsq[4] = {0.f, 0.f, 0.f, 0.f};
    #pragma unroll
    for (int lt = 0; lt < 4; ++lt) {
        f32x4 acc = *(const f32x4*)(&biasS[obase]);
        #pragma unroll
        for (int kt = 0; kt < 3; ++kt) {
            short8 bf = *(const short8*)(&Bap[(lt * 16 + m16) * 104 + kt * 32 + g4 * 8]);
            acc = __builtin_amdgcn_mfma_f32_16x16x32_bf16(aq[kt], bf, acc, 0, 0, 0);
        }
        #pragma unroll
        for (int r = 0; r < 4; ++r) {
            float v = fmaxf(acc[r], 0.f);
            vsum[r] += v; vsq[r] += v * v;
        }
    }
    #pragma unroll
    for (int r = 0; r < 4; ++r) {
        vsum[r] = sum16_dpp(vsum[r]);
        vsq[r]  = sum16_dpp(vsq[r]);
    }
    if (m16 == 15) {
        #pragma unroll
        for (int r = 0; r < 4; ++r) {
            muS1[b * 128 + obase + r] = vsum[r];
            muQ1[b * 128 + obase + r] = vsq[r];
        }
    }

    // UE: 2 k-tiles, stats only
    float usum[4] = {0.f, 0.f, 0.f, 0.f}, usq[4] = {0.f, 0.f, 0.f, 0.f};
    #pragma unroll
    for (int nt = 0; nt < 2; ++nt) {
        f32x4 acc = *(const f32x4*)(&biasS[64 + obase]);
        #pragma unroll
        for (int kt = 0; kt < 3; ++kt) {
            short8 bf = *(const short8*)(&Bue[(nt * 16 + m16) * 104 + kt * 32 + g4 * 8]);
            acc = __builtin_amdgcn_mfma_f32_16x16x32_bf16(aqu[kt], bf, acc, 0, 0, 0);
        }
        #pragma unroll
        for (int r = 0; r < 4; ++r) {
            float v = fmaxf(acc[r], 0.f);
            usum[r] += v; usq[r] += v * v;
        }
    }
    #pragma unroll
    for (int r = 0; r < 4; ++r) {
        usum[r] = sum16_dpp(usum[r]);
        usq[r]  = sum16_dpp(usq[r]);
    }
    if (m16 == 15) {
        #pragma unroll
        for (int r = 0; r < 4; ++r) {
            muS1[b * 128 + 64 + obase + r] = usum[r];
            muQ1[b * 128 + 64 + obase + r] = usq[r];
        }
    }
}

// ---------------------------------------------------------------------------
__global__ __launch_bounds__(256, 8) void bn_finalize_kernel(
    const float* __restrict__ muS, const float* __restrict__ muQ,
    const float* __restrict__ gamma, const float* __restrict__ beta,
    float* __restrict__ coef) {
    __shared__ float redS[4], redQ[4];
    int ch = blockIdx.x;
    int tid = threadIdx.x;
    float s = 0.f, q = 0.f;
    for (int j = tid; j < 1024; j += 256) {
        s += muS[j * 128 + ch];
        q += muQ[j * 128 + ch];
    }
    s = reduce64(s);
    q = reduce64(q);
    int wave = tid >> 6, lane = tid & 63;
    if (lane == 0) { redS[wave] = s; redQ[wave] = q; }
    __syncthreads();
    if (tid == 0) {
        s = redS[0] + redS[1] + redS[2] + redS[3];
        q = redQ[0] + redQ[1] + redQ[2] + redQ[3];
        bool ap = ch < 64;
        int o = ap ? ch : ch - 64;
        float cnt = ap ? (float)(B_TOT * L_DIM) : (float)(B_TOT * K_DIM);
        float m = s / cnt;
        float var = q / cnt - m * m;
        float sc = gamma[o] / sqrtf(var + EPS_BN);
        if (ap) { coef[o] = sc;       coef[64 + o] = beta[o] - m * sc; }
        else    { coef[128 + o] = sc; coef[192 + o] = beta[o] - m * sc; }
    }
}

// ---------------------------------------------------------------------------
// Out layer, fully fused: recompute A1 via MFMA (stage A0bn -> MFMA ph1),
// BN-fold coefB into bf16 LDS B2 tile, MFMA ph2 against Qpack_o, biasO
// C-init in-kernel; then row-norm + Fhat. Bap and sV share one LDS region
// (Bap dead after ph1, sV born after ph2) -> LDS 36->28 KB, (256,4) for
// >=4 blocks/CU phase overlap.
// ---------------------------------------------------------------------------
__global__ __launch_bounds__(256, 4) void out_fin_kernel(
    const float* __restrict__ Hmk,
    const unsigned short* __restrict__ Qpack_ap,
    const unsigned short* __restrict__ Qpack_o,
    const float* __restrict__ P0,
    const float* __restrict__ Qh1,   // Q2a rows for biasA
    const float* __restrict__ Qo,    // Q2o rows for biasO
    const float* __restrict__ coefA,
    const float* __restrict__ coefB,
    const float* __restrict__ muS0,
    const float* __restrict__ muS1,
    const float* __restrict__ Vhat,
    float* __restrict__ out) {
    __shared__ union {
        unsigned short Bap[64 * 104];   // used through MFMA phase 1
        float sV[32 * 65];              // used from MFMA phase 2 onward
    } u;
    __shared__ unsigned short B2[64 * 104];
    __shared__ float mubnA[64], mubnB[64];
    __shared__ float biasA_S[64], biasO_S[32];
    __shared__ float cB[128];
    __shared__ float inv[32];
    int b = blockIdx.x, t = threadIdx.x;
    int lane = t & 63, w = t >> 6;

    // ---- stage BN(A0_ap) into Bap; Hmk cols into both Bap and B2 ----
    {
        int l = lane, i0 = w << 4;
        float hmk[8];
        #pragma unroll
        for (int c = 0; c < 8; ++c) hmk[c] = Hmk[(size_t)b * 512 + c * 64 + l];
        unsigned short tmp[16];
        #pragma unroll
        for (int m = 0; m < 16; ++m) {
            int i = i0 + m;
            float4 p0 = *(const float4*)(P0 + i * 8);
            float4 p1 = *(const float4*)(P0 + i * 8 + 4);
            float pa = p0.x * hmk[0] + p0.y * hmk[1] + p0.z * hmk[2] + p0.w * hmk[3]
                     + p1.x * hmk[4] + p1.y * hmk[5] + p1.z * hmk[6] + p1.w * hmk[7];
            float a0 = fmaxf(0.1f * pa, 0.f);
            tmp[m] = f2bf(a0 * coefA[i] + coefA[64 + i]);
        }
        short8 s0, s1;
        #pragma unroll
        for (int j = 0; j < 8; ++j) { s0[j] = (short)tmp[j]; s1[j] = (short)tmp[8 + j]; }
        *(short8*)(&u.Bap[l * 104 + i0]) = s0;
        *(short8*)(&u.Bap[l * 104 + i0 + 8]) = s1;
        if (w == 0) {
            #pragma unroll
            for (int c = 0; c < 8; ++c) {
                unsigned short hb = f2bf(hmk[c]);
                u.Bap[l * 104 + 64 + c] = hb;
                B2[l * 104 + 64 + c]    = hb;
            }
            #pragma unroll
            for (int c = 72; c < 96; ++c) { u.Bap[l * 104 + c] = 0; B2[l * 104 + c] = 0; }
        }
    }
    if (t < 64)  mubnA[t] = muS0[b * 128 + 64 + t] * (1.0f / 32.0f) * coefA[128 + t] + coefA[192 + t];
    else if (t < 128) {
        int i = t - 64;
        mubnB[i] = muS1[b * 128 + 64 + i] * (1.0f / 32.0f) * coefB[128 + i] + coefB[192 + i];
    } else {
        cB[t - 128] = coefB[t - 128];   // scAP[0..63] shAP[64..127]
    }
    __syncthreads();

    // ---- bias dots ----
    if (t < 64) {
        const float4* Qrow = (const float4*)(Qh1 + 4096 + t * 64);  // Q2a row
        float sa = 0.f, sb = 0.f, sc2 = 0.f, sd = 0.f;
        #pragma unroll
        for (int j = 0; j < 16; ++j) {
            float4 q = Qrow[j];
            sa += q.x * mubnA[4 * j];
            sb += q.y * mubnA[4 * j + 1];
            sc2 += q.z * mubnA[4 * j + 2];
            sd += q.w * mubnA[4 * j + 3];
        }
        biasA_S[t] = 2.f * ((sa + sb) + (sc2 + sd));
    } else if (t < 96) {
        int o = t - 64;
        const float4* Qrow = (const float4*)(Qo + OUT_K * 64 + o * 64);  // Q2o row
        float sa = 0.f, sb = 0.f, sc2 = 0.f, sd = 0.f;
        #pragma unroll
        for (int j = 0; j < 16; ++j) {
            float4 q = Qrow[j];
            sa += q.x * mubnB[4 * j];
            sb += q.y * mubnB[4 * j + 1];
            sc2 += q.z * mubnB[4 * j + 2];
            sd += q.w * mubnB[4 * j + 3];
        }
        biasO_S[o] = 2.f * ((sa + sb) + (sc2 + sd));
    }
    __syncthreads();

    int m16 = lane & 15, g4 = lane >> 4;
    int obase = w * 16 + g4 * 4;

    // ---- MFMA phase 1: A1 = relu(Qpack_ap @ Bap + biasA); BN-fold -> B2 ----
    {
        short8 aq[3];
        #pragma unroll
        for (int kt = 0; kt < 3; ++kt)
            aq[kt] = *(const short8*)(Qpack_ap + (((kt * 4 + w) * 64 + lane) << 3));
        float scb[4], shb[4];
        #pragma unroll
        for (int r = 0; r < 4; ++r) { scb[r] = cB[obase + r]; shb[r] = cB[64 + obase + r]; }
        #pragma unroll
        for (int lt = 0; lt < 4; ++lt) {
            f32x4 acc = *(const f32x4*)(&biasA_S[obase]);
            #pragma unroll
            for (int kt = 0; kt < 3; ++kt) {
                short8 bf = *(const short8*)(&u.Bap[(lt * 16 + m16) * 104 + kt * 32 + g4 * 8]);
                acc = __builtin_amdgcn_mfma_f32_16x16x32_bf16(aq[kt], bf, acc, 0, 0, 0);
            }
            int lsp = lt * 16 + m16;
            short4v pk;
            #pragma unroll
            for (int r = 0; r < 4; ++r) {
                float v = fmaxf(acc[r], 0.f);
                pk[r] = (short)f2bf(v * scb[r] + shb[r]);
            }
            *(short4v*)(&B2[lsp * 104 + obase]) = pk;
        }
    }
    __syncthreads();   // Bap dead after this point; u.sV becomes live

    // ---- MFMA phase 2: V = Qpack_o @ B2 + biasO -> sV ----
    {
        int ot = w & 1;
        short8 aq[3];
        #pragma unroll
        for (int kt = 0; kt < 3; ++kt)
            aq[kt] = *(const short8*)(Qpack_o + (((kt * 2 + ot) * 64 + lane) << 3));
        int ch0 = ot * 16 + g4 * 4;
        #pragma unroll
        for (int h = 0; h < 2; ++h) {
            int lt = (w >> 1) + 2 * h;
            f32x4 acc = *(const f32x4*)(&biasO_S[ch0]);
            #pragma unroll
            for (int kt = 0; kt < 3; ++kt) {
                short8 bf = *(const short8*)(&B2[(lt * 16 + m16) * 104 + kt * 32 + g4 * 8]);
                acc = __builtin_amdgcn_mfma_f32_16x16x32_bf16(aq[kt], bf, acc, 0, 0, 0);
            }
            int l = lt * 16 + m16;
            #pragma unroll
            for (int r = 0; r < 4; ++r)
                u.sV[(ch0 + r) * 65 + l] = acc[r];
        }
    }
    __syncthreads();

    // ---- row norm + Fhat ----
    if (t < 32) {
        float s = 0.f;
        #pragma unroll
        for (int l = 0; l < 64; ++l) { float x = u.sV[t * 65 + l]; s += x * x; }
        inv[t] = 8.0f / sqrtf(s);
    }
    __syncthreads();
    const float4* vh4 = (const float4*)(Vhat + (size_t)b * 8192);
    float4* o4 = (float4*)out + (size_t)b * 2048;
    for (int j = t; j < 2048; j += 256) {
        int l = j >> 5, kk = j & 31;
        float p = u.sV[kk * 65 + l] * inv[kk];
        float4 x = vh4[j];
        x.x *= p; x.y *= p; x.z *= p; x.w *= p;
        o4[j] = x;
    }
}

// ---------------------------------------------------------------------------
extern "C" void kernel_launch(void* const* d_in, const int* in_sizes, int n_in,
                              void* d_out, int out_size, void* d_ws, size_t ws_size,
                              hipStream_t stream) {
    const float* Hr        = (const float*)d_in[0];
    const float* Hi        = (const float*)d_in[1];
    const float* Vhat      = (const float*)d_in[2];
    const float* Qs_hidden = (const float*)d_in[3];
    const float* Ps_hidden = (const float*)d_in[4];
    const float* Qs_out    = (const float*)d_in[5];
    const float* Ps_out    = (const float*)d_in[6];
    const float* bn_gamma  = (const float*)d_in[7];
    const float* bn_beta   = (const float*)d_in[8];
    float* out = (float*)d_out;

    float* ws    = (float*)d_ws;
    float* Hmk   = ws;                    // 1024*512
    float* Hml   = Hmk + 524288;          // 1024*256
    float* muS0  = Hml + 262144;          // 1024*128
    float* muQ0  = muS0 + 131072;         // 1024*128
    float* muS1  = muQ0 + 131072;         // 1024*128
    float* muQ1  = muS1 + 131072;         // 1024*128
    float* coefA = muQ1 + 131072;         // 256
    float* coefB = coefA + 256;           // 256
    unsigned short* Qpack_ap = (unsigned short*)(coefB + 256);  // 6144
    unsigned short* Qpack_ue = Qpack_ap + 6144;                 // 6144
    unsigned short* Qpack_o  = Qpack_ue + 6144;                 // 3072

    // 1) hmeans + layer-0 stats + weight prep
    hipLaunchKernelGGL(hmeans_l0_kernel, dim3(B_TOT + 1), dim3(256), 0, stream,
                       Hr, Hi, Hmk, Hml, Ps_hidden, muS0, muQ0,
                       Qs_hidden + 4 * 4096, Ps_hidden + 2 * 512, Qs_out, Ps_out,
                       Qpack_ap, Qpack_ue, Qpack_o);
    // 2) BN coefA
    hipLaunchKernelGGL(bn_finalize_kernel, dim3(128), dim3(256), 0, stream,
                       muS0, muQ0, bn_gamma, bn_beta, coefA);
    // 3) layer-1 stats (bias fused; no activation store)
    hipLaunchKernelGGL(l1stats_kernel, dim3(B_TOT), dim3(256), 0, stream,
                       Hmk, Hml, Qpack_ap, Qpack_ue, Ps_hidden,
                       Qs_hidden + 4 * 4096, coefA, muS0, muS1, muQ1);
    // 4) BN coefB
    hipLaunchKernelGGL(bn_finalize_kernel, dim3(128), dim3(256), 0, stream,
                       muS1, muQ1, bn_gamma + 64, bn_beta + 64, coefB);
    // 5) out layer (A1 recomputed in-kernel) + norm + Fhat
    hipLaunchKernelGGL(out_fin_kernel, dim3(B_TOT), dim3(256), 0, stream,
                       Hmk, Qpack_ap, Qpack_o, Ps_hidden,
                       Qs_hidden + 4 * 4096, Qs_out, coefA, coefB,
                       muS0, muS1, Vhat, out);
}

// Round 18
// 69.453 us; speedup vs baseline: 1.0027x; 1.0027x over previous
//
#include <hip/hip_runtime.h>

#define B_TOT 1024   // BATCH * nbr = 64 * 16
#define L_DIM 64
#define K_DIM 32
#define OUT_K 32
#define EPS_BN 1e-5f

typedef __attribute__((ext_vector_type(8))) short short8;
typedef __attribute__((ext_vector_type(4))) short short4v;
typedef __attribute__((ext_vector_type(4))) float f32x4;

__device__ __forceinline__ float reduce64(float v) {
    #pragma unroll
    for (int w = 1; w < 64; w <<= 1) v += __shfl_xor(v, w);
    return v;
}

// DPP fused-add reduction step (VALU, zero LDS-pipe traffic).
template<int CTRL, int RM>
__device__ __forceinline__ float dppadd(float v) {
    return v + __int_as_float(__builtin_amdgcn_update_dpp(
        0, __float_as_int(v), CTRL, RM, 0xF, true));
}
// wave64 sum -> lane 63
__device__ __forceinline__ float sum64_dpp(float v) {
    v = dppadd<0x111, 0xF>(v);
    v = dppadd<0x112, 0xF>(v);
    v = dppadd<0x114, 0xF>(v);
    v = dppadd<0x118, 0xF>(v);
    v = dppadd<0x142, 0xA>(v);  // row_bcast15
    v = dppadd<0x143, 0xC>(v);  // row_bcast31
    return v;
}
// 32-lane sums -> lanes 31 and 63
__device__ __forceinline__ float sum32_dpp(float v) {
    v = dppadd<0x111, 0xF>(v);
    v = dppadd<0x112, 0xF>(v);
    v = dppadd<0x114, 0xF>(v);
    v = dppadd<0x118, 0xF>(v);
    v = dppadd<0x142, 0xA>(v);
    return v;
}
// 16-lane (row) sums -> lane 15 of each row
__device__ __forceinline__ float sum16_dpp(float v) {
    v = dppadd<0x111, 0xF>(v);
    v = dppadd<0x112, 0xF>(v);
    v = dppadd<0x114, 0xF>(v);
    v = dppadd<0x118, 0xF>(v);
    return v;
}

__device__ __forceinline__ unsigned short f2bf(float x) {
    unsigned int u = __float_as_uint(x);
    u += 0x7FFF + ((u >> 16) & 1);   // RNE
    return (unsigned short)(u >> 16);
}

// ---------------------------------------------------------------------------
// hmeans + fused layer-0 stats + (block B_TOT) weight prep (DPP reductions).
// ---------------------------------------------------------------------------
__global__ __launch_bounds__(256, 4) void hmeans_l0_kernel(
    const float* __restrict__ Hr, const float* __restrict__ Hi,
    float* __restrict__ Hmk, float* __restrict__ Hml,
    const float* __restrict__ P0,   // layer0: P1a | P1u
    float* __restrict__ muS, float* __restrict__ muQ,
    const float* __restrict__ Qh1,  // layer-1 Q base (prep)
    const float* __restrict__ P1h,  // layer-1 P base (prep)
    const float* __restrict__ Qo,   // out-layer Q base (prep)
    const float* __restrict__ Po,   // out-layer P base (prep)
    unsigned short* __restrict__ Qpack_ap,
    unsigned short* __restrict__ Qpack_ue,
    unsigned short* __restrict__ Qpack_o) {
    int b = blockIdx.x, tid = threadIdx.x;

    if (b == B_TOT) {
        // ---- weight-prep block ----
        const float* Q1a = Qh1;
        const float* Q1u = Qh1 + 2 * 4096;
        const float* P1a = P1h;
        const float* P1u = P1h + 512;
        for (int idx = tid; idx < 6144; idx += 256) {
            int j = idx & 7, lane = (idx >> 3) & 63, ot = (idx >> 9) & 3, kt = idx >> 11;
            int m = lane & 15, kloc = (lane >> 4) * 8 + j;
            int o = ot * 16 + m, k = kt * 32 + kloc;
            float va = 0.f, vu = 0.f;
            if (k < 64)      { va = 2.0f * Q1a[o * 64 + k]; vu = 2.0f * Q1u[o * 64 + k]; }
            else if (k < 72) { va = 0.1f * P1a[o * 8 + (k - 64)]; vu = 0.1f * P1u[o * 8 + (k - 64)]; }
            Qpack_ap[idx] = f2bf(va);
            Qpack_ue[idx] = f2bf(vu);
        }
        // out-layer pack: 2 o-tiles x 3 k-tiles; cols 0..63 = 2*Q1o,
        // 64..71 = 0.1*P1o, 72..95 = 0
        for (int idx = tid; idx < 3072; idx += 256) {
            int j = idx & 7, lane = (idx >> 3) & 63, ot = (idx >> 9) & 1, kt = idx >> 10;
            int m = lane & 15, kloc = (lane >> 4) * 8 + j;
            int o = ot * 16 + m, k = kt * 32 + kloc;
            float v = 0.f;
            if (k < 64)      v = 2.0f * Qo[o * 64 + k];
            else if (k < 72) v = 0.1f * Po[o * 8 + (k - 64)];
            Qpack_o[idx] = f2bf(v);
        }
        return;
    }

    __shared__ float hmkS[512];      // [c][l]
    __shared__ float hmlS[256];      // [c][k]
    __shared__ float4 wpart[4][32];  // [wave][k]
    int w = tid >> 6, lane = tid & 63;
    int g = tid >> 5, k = tid & 31;

    for (int ri = 0; ri < 2; ++ri) {
        const float4* src4 = (const float4*)((ri ? Hi : Hr) + (size_t)b * 8192);
        float4 v[8];
        #pragma unroll
        for (int s = 0; s < 8; ++s) v[s] = src4[tid + 256 * s];

        float4 part = v[0];
        #pragma unroll
        for (int s = 1; s < 8; ++s) {
            part.x += v[s].x; part.y += v[s].y;
            part.z += v[s].z; part.w += v[s].w;
        }

        #pragma unroll
        for (int s = 0; s < 8; ++s) {
            float rx = sum32_dpp(v[s].x);
            float ry = sum32_dpp(v[s].y);
            float rz = sum32_dpp(v[s].z);
            float rw = sum32_dpp(v[s].w);
            if ((lane & 31) == 31) {
                int l = g + 8 * s;
                const float sc = 1.0f / 32.0f;
                hmkS[(ri * 4 + 0) * 64 + l] = rx * sc;
                hmkS[(ri * 4 + 1) * 64 + l] = ry * sc;
                hmkS[(ri * 4 + 2) * 64 + l] = rz * sc;
                hmkS[(ri * 4 + 3) * 64 + l] = rw * sc;
            }
        }

        part.x += __shfl_xor(part.x, 32);
        part.y += __shfl_xor(part.y, 32);
        part.z += __shfl_xor(part.z, 32);
        part.w += __shfl_xor(part.w, 32);
        if (lane < 32) wpart[w][k] = part;
        __syncthreads();
        if (tid < 128) {
            int kk = tid >> 2, u = tid & 3;
            float s = ((const float*)&wpart[0][kk])[u]
                    + ((const float*)&wpart[1][kk])[u]
                    + ((const float*)&wpart[2][kk])[u]
                    + ((const float*)&wpart[3][kk])[u];
            hmlS[(ri * 4 + u) * 32 + kk] = s * (1.0f / 64.0f);
        }
        __syncthreads();
    }

    Hmk[(size_t)b * 512 + tid]       = hmkS[tid];
    Hmk[(size_t)b * 512 + 256 + tid] = hmkS[256 + tid];
    Hml[(size_t)b * 256 + tid]       = hmlS[tid];

    // ---- layer-0 stats ----
    int o0 = __builtin_amdgcn_readfirstlane(w << 4);
    float hmk[8], hml[8];
    #pragma unroll
    for (int c = 0; c < 8; ++c) hmk[c] = hmkS[c * 64 + lane];
    #pragma unroll
    for (int c = 0; c < 8; ++c) hml[c] = hmlS[c * 32 + (lane & 31)];

    for (int h = 0; h < 2; ++h) {
        float vs[8], qs[8];
        #pragma unroll
        for (int mm = 0; mm < 8; ++mm) {
            int o = o0 + h * 8 + mm;
            float4 p0 = *(const float4*)(P0 + o * 8);
            float4 p1 = *(const float4*)(P0 + o * 8 + 4);
            float pa = p0.x * hmk[0] + p0.y * hmk[1] + p0.z * hmk[2] + p0.w * hmk[3]
                     + p1.x * hmk[4] + p1.y * hmk[5] + p1.z * hmk[6] + p1.w * hmk[7];
            float v = fmaxf(0.1f * pa, 0.f);
            vs[mm] = sum64_dpp(v);
            qs[mm] = sum64_dpp(v * v);
        }
        if (lane == 63) {
            #pragma unroll
            for (int mm = 0; mm < 8; ++mm) {
                muS[b * 128 + o0 + h * 8 + mm] = vs[mm];
                muQ[b * 128 + o0 + h * 8 + mm] = qs[mm];
            }
        }
    }
    for (int h = 0; h < 2; ++h) {
        float vs[8], qs[8];
        #pragma unroll
        for (int mm = 0; mm < 8; ++mm) {
            int o = o0 + h * 8 + mm;
            float4 p0 = *(const float4*)(P0 + 512 + o * 8);
            float4 p1 = *(const float4*)(P0 + 512 + o * 8 + 4);
            float pu = p0.x * hml[0] + p0.y * hml[1] + p0.z * hml[2] + p0.w * hml[3]
                     + p1.x * hml[4] + p1.y * hml[5] + p1.z * hml[6] + p1.w * hml[7];
            float v = fmaxf(0.1f * pu, 0.f);
            vs[mm] = sum64_dpp(v);
            qs[mm] = sum64_dpp(v * v);
        }
        if (lane == 63) {
            #pragma unroll
            for (int mm = 0; mm < 8; ++mm) {
                muS[b * 128 + 64 + o0 + h * 8 + mm] = vs[mm] * 0.5f;
                muQ[b * 128 + 64 + o0 + h * 8 + mm] = qs[mm] * 0.5f;
            }
        }
    }
}

// ---------------------------------------------------------------------------
// Layer-1 stats via MFMA (no activation store; biasA computed in-kernel).
// One block per b (4 waves).
// ---------------------------------------------------------------------------
__global__ __launch_bounds__(256, 2) void l1stats_kernel(
    const float* __restrict__ Hmk, const float* __restrict__ Hml,
    const unsigned short* __restrict__ Qpack_ap,
    const unsigned short* __restrict__ Qpack_ue,
    const float* __restrict__ P0,
    const float* __restrict__ Qh1,     // layer-1 Q base (Q2a/Q2u rows)
    const float* __restrict__ coefA,
    const float* __restrict__ muS0,    // layer-0 raw sums
    float* __restrict__ muS1, float* __restrict__ muQ1) {
    __shared__ unsigned short Bap[64 * 104];
    __shared__ unsigned short Bue[32 * 104];
    __shared__ float mubn[128];
    __shared__ float biasS[128];
    int b = blockIdx.x, t = threadIdx.x;

    // ---- stage BN(A0_ap) + mubn ----
    {
        int l = t & 63, wid = t >> 6, i0 = wid << 4;
        float hmk[8];
        #pragma unroll
        for (int c = 0; c < 8; ++c) hmk[c] = Hmk[(size_t)b * 512 + c * 64 + l];
        unsigned short tmp[16];
        #pragma unroll
        for (int m = 0; m < 16; ++m) {
            int i = i0 + m;
            float4 p0 = *(const float4*)(P0 + i * 8);
            float4 p1 = *(const float4*)(P0 + i * 8 + 4);
            float pa = p0.x * hmk[0] + p0.y * hmk[1] + p0.z * hmk[2] + p0.w * hmk[3]
                     + p1.x * hmk[4] + p1.y * hmk[5] + p1.z * hmk[6] + p1.w * hmk[7];
            float a0 = fmaxf(0.1f * pa, 0.f);
            tmp[m] = f2bf(a0 * coefA[i] + coefA[64 + i]);
        }
        short8 s0, s1;
        #pragma unroll
        for (int j = 0; j < 8; ++j) { s0[j] = (short)tmp[j]; s1[j] = (short)tmp[8 + j]; }
        *(short8*)(&Bap[l * 104 + i0]) = s0;
        *(short8*)(&Bap[l * 104 + i0 + 8]) = s1;
        if (wid == 0) {
            #pragma unroll
            for (int c = 0; c < 8; ++c) Bap[l * 104 + 64 + c] = f2bf(hmk[c]);
            #pragma unroll
            for (int c = 72; c < 96; ++c) Bap[l * 104 + c] = 0;
        }
    }
    {
        int k = t & 31, g = t >> 5, i0 = g << 3;
        float hml[8];
        #pragma unroll
        for (int c = 0; c < 8; ++c) hml[c] = Hml[(size_t)b * 256 + c * 32 + k];
        unsigned short tu[8];
        #pragma unroll
        for (int m = 0; m < 8; ++m) {
            int i = i0 + m;
            float4 p0 = *(const float4*)(P0 + 512 + i * 8);
            float4 p1 = *(const float4*)(P0 + 512 + i * 8 + 4);
            float pu = p0.x * hml[0] + p0.y * hml[1] + p0.z * hml[2] + p0.w * hml[3]
                     + p1.x * hml[4] + p1.y * hml[5] + p1.z * hml[6] + p1.w * hml[7];
            float a0 = fmaxf(0.1f * pu, 0.f);
            tu[m] = f2bf(a0 * coefA[128 + i] + coefA[192 + i]);
        }
        short8 s0;
        #pragma unroll
        for (int j = 0; j < 8; ++j) s0[j] = (short)tu[j];
        *(short8*)(&Bue[k * 104 + i0]) = s0;
        if (t < 32) {
            #pragma unroll
            for (int c = 0; c < 8; ++c) Bue[k * 104 + 64 + c] = f2bf(hml[c]);
            #pragma unroll
            for (int c = 72; c < 96; ++c) Bue[k * 104 + c] = 0;
        }
    }
    if (t < 128) {
        float raw = muS0[b * 128 + t];
        mubn[t] = (t < 64)
            ? raw * (1.0f / 64.0f) * coefA[t] + coefA[64 + t]
            : raw * (1.0f / 32.0f) * coefA[64 + t] + coefA[128 + t];
    }
    __syncthreads();

    // ---- bias dots: biasS[o]=2*Q2a[o,:]@mubnUE, biasS[64+o]=2*Q2u[o,:]@mubnAP
    if (t < 128) {
        const float* Qm = (t < 64) ? (Qh1 + 4096) : (Qh1 + 3 * 4096);
        const float* mu = (t < 64) ? (mubn + 64) : mubn;
        int o = t & 63;
        const float4* Qrow = (const float4*)(Qm + o * 64);
        float sa = 0.f, sb = 0.f, sc2 = 0.f, sd = 0.f;
        #pragma unroll
        for (int j = 0; j < 16; ++j) {
            float4 q = Qrow[j];
            sa += q.x * mu[4 * j];
            sb += q.y * mu[4 * j + 1];
            sc2 += q.z * mu[4 * j + 2];
            sd += q.w * mu[4 * j + 3];
        }
        biasS[t] = 2.f * ((sa + sb) + (sc2 + sd));
    }
    __syncthreads();

    int lane = t & 63, w = t >> 6;
    int m16 = lane & 15, g4 = lane >> 4;
    int obase = w * 16 + g4 * 4;

    short8 aq[3], aqu[3];
    #pragma unroll
    for (int kt = 0; kt < 3; ++kt) {
        aq[kt]  = *(const short8*)(Qpack_ap + (((kt * 4 + w) * 64 + lane) << 3));
        aqu[kt] = *(const short8*)(Qpack_ue + (((kt * 4 + w) * 64 + lane) << 3));
    }

    // AP: 4 l-tiles, stats only
    float vsum[4] = {0.f, 0.f, 0.f, 0.f}, vsq[4] = {0.f, 0.f, 0.f, 0.f};
    #pragma unroll
    for (int lt = 0; lt < 4; ++lt) {
        f32x4 acc = *(const f32x4*)(&biasS[obase]);
        #pragma unroll
        for (int kt = 0; kt < 3; ++kt) {
            short8 bf = *(const short8*)(&Bap[(lt * 16 + m16) * 104 + kt * 32 + g4 * 8]);
            acc = __builtin_amdgcn_mfma_f32_16x16x32_bf16(aq[kt], bf, acc, 0, 0, 0);
        }
        #pragma unroll
        for (int r = 0; r < 4; ++r) {
            float v = fmaxf(acc[r], 0.f);
            vsum[r] += v; vsq[r] += v * v;
        }
    }
    #pragma unroll
    for (int r = 0; r < 4; ++r) {
        vsum[r] = sum16_dpp(vsum[r]);
        vsq[r]  = sum16_dpp(vsq[r]);
    }
    if (m16 == 15) {
        #pragma unroll
        for (int r = 0; r < 4; ++r) {
            muS1[b * 128 + obase + r] = vsum[r];
            muQ1[b * 128 + obase + r] = vsq[r];
        }
    }

    // UE: 2 k-tiles, stats only
    float usum[4] = {0.f, 0.f, 0.f, 0.f}, usq[4] = {0.f, 0.f, 0.f, 0.f};
    #pragma unroll
    for (int nt = 0; nt < 2; ++nt) {
        f32x4 acc = *(const f32x4*)(&biasS[64 + obase]);
        #pragma unroll
        for (int kt = 0; kt < 3; ++kt) {
            short8 bf = *(const short8*)(&Bue[(nt * 16 + m16) * 104 + kt * 32 + g4 * 8]);
            acc = __builtin_amdgcn_mfma_f32_16x16x32_bf16(aqu[kt], bf, acc, 0, 0, 0);
        }
        #pragma unroll
        for (int r = 0; r < 4; ++r) {
            float v = fmaxf(acc[r], 0.f);
            usum[r] += v; usq[r] += v * v;
        }
    }
    #pragma unroll
    for (int r = 0; r < 4; ++r) {
        usum[r] = sum16_dpp(usum[r]);
        usq[r]  = sum16_dpp(usq[r]);
    }
    if (m16 == 15) {
        #pragma unroll
        for (int r = 0; r < 4; ++r) {
            muS1[b * 128 + 64 + obase + r] = usum[r];
            muQ1[b * 128 + 64 + obase + r] = usq[r];
        }
    }
}

// ---------------------------------------------------------------------------
__global__ __launch_bounds__(256, 8) void bn_finalize_kernel(
    const float* __restrict__ muS, const float* __restrict__ muQ,
    const float* __restrict__ gamma, const float* __restrict__ beta,
    float* __restrict__ coef) {
    __shared__ float redS[4], redQ[4];
    int ch = blockIdx.x;
    int tid = threadIdx.x;
    float s = 0.f, q = 0.f;
    for (int j = tid; j < 1024; j += 256) {
        s += muS[j * 128 + ch];
        q += muQ[j * 128 + ch];
    }
    s = reduce64(s);
    q = reduce64(q);
    int wave = tid >> 6, lane = tid & 63;
    if (lane == 0) { redS[wave] = s; redQ[wave] = q; }
    __syncthreads();
    if (tid == 0) {
        s = redS[0] + redS[1] + redS[2] + redS[3];
        q = redQ[0] + redQ[1] + redQ[2] + redQ[3];
        bool ap = ch < 64;
        int o = ap ? ch : ch - 64;
        float cnt = ap ? (float)(B_TOT * L_DIM) : (float)(B_TOT * K_DIM);
        float m = s / cnt;
        float var = q / cnt - m * m;
        float sc = gamma[o] / sqrtf(var + EPS_BN);
        if (ap) { coef[o] = sc;       coef[64 + o] = beta[o] - m * sc; }
        else    { coef[128 + o] = sc; coef[192 + o] = beta[o] - m * sc; }
    }
}

// ---------------------------------------------------------------------------
// Out layer, fully fused: recompute A1 via MFMA (stage A0bn -> MFMA ph1),
// BN-fold coefB into bf16 LDS B2 tile, MFMA ph2 against Qpack_o
// (K-aug: cols 0..63=2*Q1o, 64..71=0.1*P1o), biasO C-init computed
// in-kernel; then row-norm + Fhat.
// ---------------------------------------------------------------------------
__global__ __launch_bounds__(256, 2) void out_fin_kernel(
    const float* __restrict__ Hmk,
    const unsigned short* __restrict__ Qpack_ap,
    const unsigned short* __restrict__ Qpack_o,
    const float* __restrict__ P0,
    const float* __restrict__ Qh1,   // Q2a rows for biasA
    const float* __restrict__ Qo,    // Q2o rows for biasO
    const float* __restrict__ coefA,
    const float* __restrict__ coefB,
    const float* __restrict__ muS0,
    const float* __restrict__ muS1,
    const float* __restrict__ Vhat,
    float* __restrict__ out) {
    __shared__ unsigned short Bap[64 * 104];
    __shared__ unsigned short B2[64 * 104];
    __shared__ float sV[32 * 65];
    __shared__ float mubnA[64], mubnB[64];
    __shared__ float biasA_S[64], biasO_S[32];
    __shared__ float cB[128];
    __shared__ float inv[32];
    int b = blockIdx.x, t = threadIdx.x;
    int lane = t & 63, w = t >> 6;

    // ---- stage BN(A0_ap) into Bap; Hmk cols into both Bap and B2 ----
    {
        int l = lane, i0 = w << 4;
        float hmk[8];
        #pragma unroll
        for (int c = 0; c < 8; ++c) hmk[c] = Hmk[(size_t)b * 512 + c * 64 + l];
        unsigned short tmp[16];
        #pragma unroll
        for (int m = 0; m < 16; ++m) {
            int i = i0 + m;
            float4 p0 = *(const float4*)(P0 + i * 8);
            float4 p1 = *(const float4*)(P0 + i * 8 + 4);
            float pa = p0.x * hmk[0] + p0.y * hmk[1] + p0.z * hmk[2] + p0.w * hmk[3]
                     + p1.x * hmk[4] + p1.y * hmk[5] + p1.z * hmk[6] + p1.w * hmk[7];
            float a0 = fmaxf(0.1f * pa, 0.f);
            tmp[m] = f2bf(a0 * coefA[i] + coefA[64 + i]);
        }
        short8 s0, s1;
        #pragma unroll
        for (int j = 0; j < 8; ++j) { s0[j] = (short)tmp[j]; s1[j] = (short)tmp[8 + j]; }
        *(short8*)(&Bap[l * 104 + i0]) = s0;
        *(short8*)(&Bap[l * 104 + i0 + 8]) = s1;
        if (w == 0) {
            #pragma unroll
            for (int c = 0; c < 8; ++c) {
                unsigned short hb = f2bf(hmk[c]);
                Bap[l * 104 + 64 + c] = hb;
                B2[l * 104 + 64 + c]  = hb;
            }
            #pragma unroll
            for (int c = 72; c < 96; ++c) { Bap[l * 104 + c] = 0; B2[l * 104 + c] = 0; }
        }
    }
    if (t < 64)  mubnA[t] = muS0[b * 128 + 64 + t] * (1.0f / 32.0f) * coefA[128 + t] + coefA[192 + t];
    else if (t < 128) {
        int i = t - 64;
        mubnB[i] = muS1[b * 128 + 64 + i] * (1.0f / 32.0f) * coefB[128 + i] + coefB[192 + i];
    } else {
        cB[t - 128] = coefB[t - 128];   // scAP[0..63] shAP[64..127]
    }
    __syncthreads();

    // ---- bias dots ----
    if (t < 64) {
        const float4* Qrow = (const float4*)(Qh1 + 4096 + t * 64);  // Q2a row
        float sa = 0.f, sb = 0.f, sc2 = 0.f, sd = 0.f;
        #pragma unroll
        for (int j = 0; j < 16; ++j) {
            float4 q = Qrow[j];
            sa += q.x * mubnA[4 * j];
            sb += q.y * mubnA[4 * j + 1];
            sc2 += q.z * mubnA[4 * j + 2];
            sd += q.w * mubnA[4 * j + 3];
        }
        biasA_S[t] = 2.f * ((sa + sb) + (sc2 + sd));
    } else if (t < 96) {
        int o = t - 64;
        const float4* Qrow = (const float4*)(Qo + OUT_K * 64 + o * 64);  // Q2o row
        float sa = 0.f, sb = 0.f, sc2 = 0.f, sd = 0.f;
        #pragma unroll
        for (int j = 0; j < 16; ++j) {
            float4 q = Qrow[j];
            sa += q.x * mubnB[4 * j];
            sb += q.y * mubnB[4 * j + 1];
            sc2 += q.z * mubnB[4 * j + 2];
            sd += q.w * mubnB[4 * j + 3];
        }
        biasO_S[o] = 2.f * ((sa + sb) + (sc2 + sd));
    }
    __syncthreads();

    int m16 = lane & 15, g4 = lane >> 4;
    int obase = w * 16 + g4 * 4;

    // ---- MFMA phase 1: A1 = relu(Qpack_ap @ Bap + biasA); BN-fold -> B2 ----
    {
        short8 aq[3];
        #pragma unroll
        for (int kt = 0; kt < 3; ++kt)
            aq[kt] = *(const short8*)(Qpack_ap + (((kt * 4 + w) * 64 + lane) << 3));
        float scb[4], shb[4];
        #pragma unroll
        for (int r = 0; r < 4; ++r) { scb[r] = cB[obase + r]; shb[r] = cB[64 + obase + r]; }
        #pragma unroll
        for (int lt = 0; lt < 4; ++lt) {
            f32x4 acc = *(const f32x4*)(&biasA_S[obase]);
            #pragma unroll
            for (int kt = 0; kt < 3; ++kt) {
                short8 bf = *(const short8*)(&Bap[(lt * 16 + m16) * 104 + kt * 32 + g4 * 8]);
                acc = __builtin_amdgcn_mfma_f32_16x16x32_bf16(aq[kt], bf, acc, 0, 0, 0);
            }
            int lsp = lt * 16 + m16;
            short4v pk;
            #pragma unroll
            for (int r = 0; r < 4; ++r) {
                float v = fmaxf(acc[r], 0.f);
                pk[r] = (short)f2bf(v * scb[r] + shb[r]);
            }
            *(short4v*)(&B2[lsp * 104 + obase]) = pk;
        }
    }
    __syncthreads();

    // ---- MFMA phase 2: V = Qpack_o @ B2 + biasO -> sV ----
    {
        int ot = w & 1;
        short8 aq[3];
        #pragma unroll
        for (int kt = 0; kt < 3; ++kt)
            aq[kt] = *(const short8*)(Qpack_o + (((kt * 2 + ot) * 64 + lane) << 3));
        int ch0 = ot * 16 + g4 * 4;
        #pragma unroll
        for (int h = 0; h < 2; ++h) {
            int lt = (w >> 1) + 2 * h;
            f32x4 acc = *(const f32x4*)(&biasO_S[ch0]);
            #pragma unroll
            for (int kt = 0; kt < 3; ++kt) {
                short8 bf = *(const short8*)(&B2[(lt * 16 + m16) * 104 + kt * 32 + g4 * 8]);
                acc = __builtin_amdgcn_mfma_f32_16x16x32_bf16(aq[kt], bf, acc, 0, 0, 0);
            }
            int l = lt * 16 + m16;
            #pragma unroll
            for (int r = 0; r < 4; ++r)
                sV[(ch0 + r) * 65 + l] = acc[r];
        }
    }
    __syncthreads();

    // ---- row norm + Fhat ----
    if (t < 32) {
        float s = 0.f;
        #pragma unroll
        for (int l = 0; l < 64; ++l) { float x = sV[t * 65 + l]; s += x * x; }
        inv[t] = 8.0f / sqrtf(s);
    }
    __syncthreads();
    const float4* vh4 = (const float4*)(Vhat + (size_t)b * 8192);
    float4* o4 = (float4*)out + (size_t)b * 2048;
    for (int j = t; j < 2048; j += 256) {
        int l = j >> 5, kk = j & 31;
        float p = sV[kk * 65 + l] * inv[kk];
        float4 x = vh4[j];
        x.x *= p; x.y *= p; x.z *= p; x.w *= p;
        o4[j] = x;
    }
}

// ---------------------------------------------------------------------------
extern "C" void kernel_launch(void* const* d_in, const int* in_sizes, int n_in,
                              void* d_out, int out_size, void* d_ws, size_t ws_size,
                              hipStream_t stream) {
    const float* Hr        = (const float*)d_in[0];
    const float* Hi        = (const float*)d_in[1];
    const float* Vhat      = (const float*)d_in[2];
    const float* Qs_hidden = (const float*)d_in[3];
    const float* Ps_hidden = (const float*)d_in[4];
    const float* Qs_out    = (const float*)d_in[5];
    const float* Ps_out    = (const float*)d_in[6];
    const float* bn_gamma  = (const float*)d_in[7];
    const float* bn_beta   = (const float*)d_in[8];
    float* out = (float*)d_out;

    float* ws    = (float*)d_ws;
    float* Hmk   = ws;                    // 1024*512
    float* Hml   = Hmk + 524288;          // 1024*256
    float* muS0  = Hml + 262144;          // 1024*128
    float* muQ0  = muS0 + 131072;         // 1024*128
    float* muS1  = muQ0 + 131072;         // 1024*128
    float* muQ1  = muS1 + 131072;         // 1024*128
    float* coefA = muQ1 + 131072;         // 256
    float* coefB = coefA + 256;           // 256
    unsigned short* Qpack_ap = (unsigned short*)(coefB + 256);  // 6144
    unsigned short* Qpack_ue = Qpack_ap + 6144;                 // 6144
    unsigned short* Qpack_o  = Qpack_ue + 6144;                 // 3072

    // 1) hmeans + layer-0 stats + weight prep
    hipLaunchKernelGGL(hmeans_l0_kernel, dim3(B_TOT + 1), dim3(256), 0, stream,
                       Hr, Hi, Hmk, Hml, Ps_hidden, muS0, muQ0,
                       Qs_hidden + 4 * 4096, Ps_hidden + 2 * 512, Qs_out, Ps_out,
                       Qpack_ap, Qpack_ue, Qpack_o);
    // 2) BN coefA
    hipLaunchKernelGGL(bn_finalize_kernel, dim3(128), dim3(256), 0, stream,
                       muS0, muQ0, bn_gamma, bn_beta, coefA);
    // 3) layer-1 stats (bias fused; no activation store)
    hipLaunchKernelGGL(l1stats_kernel, dim3(B_TOT), dim3(256), 0, stream,
                       Hmk, Hml, Qpack_ap, Qpack_ue, Ps_hidden,
                       Qs_hidden + 4 * 4096, coefA, muS0, muS1, muQ1);
    // 4) BN coefB
    hipLaunchKernelGGL(bn_finalize_kernel, dim3(128), dim3(256), 0, stream,
                       muS1, muQ1, bn_gamma + 64, bn_beta + 64, coefB);
    // 5) out layer (A1 recomputed in-kernel) + norm + Fhat
    hipLaunchKernelGGL(out_fin_kernel, dim3(B_TOT), dim3(256), 0, stream,
                       Hmk, Qpack_ap, Qpack_o, Ps_hidden,
                       Qs_hidden + 4 * 4096, Qs_out, coefA, coefB,
                       muS0, muS1, Vhat, out);
}